// Round 13
// baseline (436.150 us; speedup 1.0000x reference)
//
#include <hip/hip_runtime.h>
#include <hip/hip_bf16.h>

// Problem constants (B,L,D)=(4,2048,768), K=12, M=1, CK=4, H=64
#define B_       4
#define L_       2048
#define D_       768
#define K_       12
#define H_       64
#define CK_      4
#define DIM_MEM_ 768
#define DMK      780        // DIM_MEM + K
#define NT       (B_*L_)    // 8192 tokens
#define NSUM     1536       // 2*K*H  (summary width)
#define NACT     2304       // K*192  (y_act width)
#define NCHUNK   16
#define CHLEN    (L_/NCHUNK)  // 128
#define PSTRIDE  132

typedef __attribute__((ext_vector_type(8))) short          bf16x8;
typedef __attribute__((ext_vector_type(8))) unsigned short u16x8;
typedef __attribute__((ext_vector_type(4))) float          f32x4;

__device__ __forceinline__ ushort f2bf(float v) {
    __hip_bfloat16 h = __float2bfloat16(v);
    return *reinterpret_cast<ushort*>(&h);
}
// fast tanh via hw exp; safe for any x
__device__ __forceinline__ float tanh_fast(float x) {
    float t = __expf(-2.f * fabsf(x));
    float r = (1.f - t) / (1.f + t);
    return copysignf(r, x);
}

// ---------------------------------------------------------------------------
// Merged prep: transpose-cast jobs (32n x 64k LDS tiles, ushort8 stores) +
// x->bf16 cast (2xfloat4 -> ushort8). r12: measured neutral vs scalar-store
// version (within noise) -- kept, theoretically better.
// remap==1: interleaved val/gate layout for the fused spectral GEMM.
// ---------------------------------------------------------------------------
struct PrepJobs {
    const float* W[6];
    ushort*      out[6];
    int ldw[6], Kd[6], colbase[6], remap[6], ntx[6];
    int start[7];
    const float* cast_in;
    ushort*      cast_out;
    int n8;                         // number of ushort8 groups in cast job
};

__global__ __launch_bounds__(256)
void prep_all(PrepJobs J)
{
    int blk = blockIdx.x;
    if (blk >= J.start[6]) {                       // cast job: 2 float4 -> ushort8
        int i = (blk - J.start[6]) * 256 + threadIdx.x;
        if (i < J.n8) {
            float4 v0 = reinterpret_cast<const float4*>(J.cast_in)[2*i];
            float4 v1 = reinterpret_cast<const float4*>(J.cast_in)[2*i + 1];
            u16x8 o;
            o[0] = f2bf(v0.x); o[1] = f2bf(v0.y); o[2] = f2bf(v0.z); o[3] = f2bf(v0.w);
            o[4] = f2bf(v1.x); o[5] = f2bf(v1.y); o[6] = f2bf(v1.z); o[7] = f2bf(v1.w);
            reinterpret_cast<u16x8*>(J.cast_out)[i] = o;
        }
        return;
    }
    int j = 0;
    while (blk >= J.start[j + 1]) ++j;
    int rel = blk - J.start[j];
    int ntx = J.ntx[j];
    int n0 = (rel % ntx) * 32, k0 = (rel / ntx) * 64;
    const float* W = J.W[j];
    int ldw = J.ldw[j], Kd = J.Kd[j], colbase = J.colbase[j], remap = J.remap[j];
    ushort* out = J.out[j];

    __shared__ float tile[64][33];                 // [k_local][n_local], +1 pad
    int tx = threadIdx.x & 31, ty = threadIdx.x >> 5;   // read: 32n x 8k, 8 iters
    int n = n0 + tx;
    int c;
    if (remap) {
        int grp = n >> 5, which = (n >> 4) & 1, nn = (grp << 4) + (n & 15);
        c = colbase + (nn / 192) * 384 + which * 192 + (nn % 192);
    } else {
        c = colbase + n;
    }
    #pragma unroll
    for (int r = 0; r < 8; ++r)
        tile[ty + r*8][tx] = W[(size_t)(k0 + ty + r*8) * ldw + c];
    __syncthreads();
    // write: thread (nl = tid>>3, kg = tid&7) emits out[n0+nl][k0+kg*8 .. +7]
    int nl = threadIdx.x >> 3, kg = threadIdx.x & 7;
    u16x8 o;
    #pragma unroll
    for (int t = 0; t < 8; ++t)
        o[t] = f2bf(tile[kg*8 + t][nl]);
    *reinterpret_cast<u16x8*>(&out[(size_t)(n0 + nl) * Kd + k0 + kg*8]) = o;
}

// ---------------------------------------------------------------------------
// global_load_lds staging macro (width 16)
// ---------------------------------------------------------------------------
#define GLOAD16(gp, dp) __builtin_amdgcn_global_load_lds( \
    (__attribute__((address_space(1))) const void*)(gp),  \
    (__attribute__((address_space(3))) void*)(dp), 16, 0, 0)

// ---------------------------------------------------------------------------
// bf16 MFMA GEMM, 1-phase pipelined + 2 blocks/CU + bijective XCD swizzle.
// Swizzle KEPT here (r10/r11 A/B: helps when streamed operand is L2-resident).
// ---------------------------------------------------------------------------
__device__ __forceinline__ void g13_stage(ushort* dst, const ushort* src, int kd)
{
    #pragma unroll
    for (int s = 0; s < 4; ++s)
        GLOAD16(src + (size_t)(32*s)*kd, dst + 2048*s);
}

__global__ __launch_bounds__(256, 2)
void gemm13_1ph(const ushort* __restrict__ A, const ushort* __restrict__ BT,
                float* __restrict__ C, int Kd, int N, int ldc)
{
    __shared__ ushort lds[32768];
    const int tid  = threadIdx.x;
    const int lane = tid & 63, wave = tid >> 6;
    const int lr = lane & 15, quad = lane >> 4, rx = lr & 7;
    const int wr = (wave >> 1) * 64, wc = (wave & 1) * 64;

    // bijective chunked XCD swizzle (nwg % 8 == 0 at all call sites)
    const int nwgx = gridDim.x;
    const int orig = blockIdx.x + blockIdx.y * nwgx;
    const int cpx  = (nwgx * gridDim.y) >> 3;
    const int swz  = (orig & 7) * cpx + (orig >> 3);
    const int m0 = (swz / nwgx) * 128, n0 = (swz % nwgx) * 128;
    const int NKT = Kd >> 6;

    const int sr = tid >> 3;             // 0..31
    const int sc = (tid & 7) ^ (sr & 7);
    const ushort* pA = A  + (size_t)(m0 + sr) * Kd + sc * 8;
    const ushort* pB = BT + (size_t)(n0 + sr) * Kd + sc * 8;

    f32x4 acc[4][4] = {};
    const int ca0 = (quad ^ rx) * 8;
    const int ca1 = ((4 + quad) ^ rx) * 8;

    g13_stage(lds + wave*512,         pA, Kd);
    g13_stage(lds + 16384 + wave*512, pB, Kd);
    asm volatile("s_waitcnt vmcnt(0)" ::: "memory");
    __builtin_amdgcn_s_barrier();

    #pragma unroll 1
    for (int g = 0; g < NKT; ++g) {
        const ushort* Ab = lds + (g & 1) * 8192;
        const ushort* Bb = lds + 16384 + (g & 1) * 8192;

        int nk = (g + 1 < NKT) ? g + 1 : NKT - 1;
        g13_stage(lds + ((g + 1) & 1) * 8192 + wave*512,         pA + nk*64, Kd);
        g13_stage(lds + 16384 + ((g + 1) & 1) * 8192 + wave*512, pB + nk*64, Kd);

        bf16x8 af[4][2], bf[4][2];
        #pragma unroll
        for (int i = 0; i < 4; ++i) {
            const ushort* p = Ab + (wr + i*16 + lr) * 64;
            af[i][0] = *reinterpret_cast<const bf16x8*>(p + ca0);
            af[i][1] = *reinterpret_cast<const bf16x8*>(p + ca1);
        }
        #pragma unroll
        for (int j = 0; j < 4; ++j) {
            const ushort* p = Bb + (wc + j*16 + lr) * 64;
            bf[j][0] = *reinterpret_cast<const bf16x8*>(p + ca0);
            bf[j][1] = *reinterpret_cast<const bf16x8*>(p + ca1);
        }
        __builtin_amdgcn_s_setprio(1);
        #pragma unroll
        for (int ks = 0; ks < 2; ++ks)
            #pragma unroll
            for (int i = 0; i < 4; ++i)
                #pragma unroll
                for (int j = 0; j < 4; ++j)
                    acc[i][j] = __builtin_amdgcn_mfma_f32_16x16x32_bf16(
                                    af[i][ks], bf[j][ks], acc[i][j], 0, 0, 0);
        __builtin_amdgcn_s_setprio(0);

        asm volatile("s_waitcnt vmcnt(0)" ::: "memory");
        __builtin_amdgcn_s_barrier();
    }

    #pragma unroll
    for (int i = 0; i < 4; ++i)
        #pragma unroll
        for (int j = 0; j < 4; ++j)
            #pragma unroll
            for (int r = 0; r < 4; ++r) {
                int row = m0 + wr + i*16 + quad*4 + r;      // m89-verified C/D map
                int col = n0 + wc + j*16 + lr;
                if (col < N)
                    C[(size_t)row * ldc + col] = acc[i][j][r];
            }
}

// ---------------------------------------------------------------------------
// Fused spectral+skip GEMM, single-phase pipelined + 2 blocks/CU (proven
// ~147us, MfmaUtil 56%, VGPR 100). No XCD swizzle (r10: hurts, 21MB B >> L2).
// ---------------------------------------------------------------------------
#define G2NKT 36   // 24 k-tiles of summary (K=1536) + 12 of x (K=768)

__device__ __forceinline__ void g2_stageA(ushort* lds_, int kt,
                                          const ushort* pAs, const ushort* pAx,
                                          int wave, int part)
{
    int ktc = kt > (G2NKT-1) ? (G2NKT-1) : kt;   // clamp src; dest parity uses kt
    const ushort* g; size_t kd;
    if (ktc < 24) { g = pAs + ktc*64;      kd = 1536; }
    else          { g = pAx + (ktc-24)*64; kd = 768;  }
    g += (size_t)(part * 64) * kd;               // rows part*64 .. part*64+63
    ushort* d = lds_ + (kt & 1) * 8192 + part * 4096 + wave * 512;
    GLOAD16(g,           d);
    GLOAD16(g + 32*kd,   d + 2048);
}

__device__ __forceinline__ void g2_stageB(ushort* lds_, int kt,
                                          const ushort* pBs, const ushort* pBx,
                                          int wave)
{
    int ktc = kt > (G2NKT-1) ? (G2NKT-1) : kt;
    const ushort* g; size_t kd;
    if (ktc < 24) { g = pBs + ktc*64;      kd = 1536; }
    else          { g = pBx + (ktc-24)*64; kd = 768;  }
    ushort* d = lds_ + 16384 + (kt & 1) * 12288 + wave * 512;
    #pragma unroll
    for (int s = 0; s < 6; ++s)
        GLOAD16(g + (size_t)(32*s)*kd, d + 2048*s);
}

__global__ __launch_bounds__(256, 2)
void gemm2_1ph(const ushort* __restrict__ Sm, const ushort* __restrict__ Xb,
               const ushort* __restrict__ WsC, const ushort* __restrict__ WiC,
               ushort* __restrict__ yact)
{
    __shared__ ushort lds[40960];
    const int tid  = threadIdx.x;
    const int lane = tid & 63, wave = tid >> 6;      // wave 0..3
    const int lr = lane & 15, quad = lane >> 4, rx = lr & 7;
    const int wr = (wave >> 1) * 64;     // 0,64
    const int wc = (wave & 1) * 96;      // 0,96
    const int m0 = blockIdx.y * 128, n0 = blockIdx.x * 192;

    const int sr = tid >> 3;             // 0..31
    const int sc = (tid & 7) ^ (sr & 7);
    const ushort* pAs = Sm  + (size_t)(m0 + sr) * 1536 + sc * 8;
    const ushort* pAx = Xb  + (size_t)(m0 + sr) * 768  + sc * 8;
    const ushort* pBs = WsC + (size_t)(n0 + sr) * 1536 + sc * 8;
    const ushort* pBx = WiC + (size_t)(n0 + sr) * 768  + sc * 8;

    f32x4 acc[4][6] = {};
    const int ca0 = (quad ^ rx) * 8;
    const int ca1 = ((4 + quad) ^ rx) * 8;

    g2_stageA(lds, 0, pAs, pAx, wave, 0);
    g2_stageA(lds, 0, pAs, pAx, wave, 1);
    g2_stageB(lds, 0, pBs, pBx, wave);
    asm volatile("s_waitcnt vmcnt(0)" ::: "memory");
    __builtin_amdgcn_s_barrier();

    #pragma unroll 1
    for (int g = 0; g < G2NKT; ++g) {
        const ushort* Ab = lds + (g & 1) * 8192;
        const ushort* Bb = lds + 16384 + (g & 1) * 12288;

        g2_stageA(lds, g + 1, pAs, pAx, wave, 0);
        g2_stageA(lds, g + 1, pAs, pAx, wave, 1);
        g2_stageB(lds, g + 1, pBs, pBx, wave);

        bf16x8 af[4][2], bfr[6][2];
        #pragma unroll
        for (int i = 0; i < 4; ++i) {
            const ushort* p = Ab + (wr + i*16 + lr) * 64;
            af[i][0] = *reinterpret_cast<const bf16x8*>(p + ca0);
            af[i][1] = *reinterpret_cast<const bf16x8*>(p + ca1);
        }
        #pragma unroll
        for (int j = 0; j < 6; ++j) {
            const ushort* p = Bb + (wc + j*16 + lr) * 64;
            bfr[j][0] = *reinterpret_cast<const bf16x8*>(p + ca0);
            bfr[j][1] = *reinterpret_cast<const bf16x8*>(p + ca1);
        }
        __builtin_amdgcn_s_setprio(1);
        #pragma unroll
        for (int ks = 0; ks < 2; ++ks)
            #pragma unroll
            for (int i = 0; i < 4; ++i)
                #pragma unroll
                for (int j = 0; j < 6; ++j)
                    acc[i][j] = __builtin_amdgcn_mfma_f32_16x16x32_bf16(
                                    af[i][ks], bfr[j][ks], acc[i][j], 0, 0, 0);
        __builtin_amdgcn_s_setprio(0);

        asm volatile("s_waitcnt vmcnt(0)" ::: "memory");
        __builtin_amdgcn_s_barrier();
    }

    // epilogue: lane-local (val,gate) pairs -> gated SiLU -> bf16
    const int vg0 = (n0 + wc) >> 5;
    #pragma unroll
    for (int i = 0; i < 4; ++i)
        #pragma unroll
        for (int p = 0; p < 3; ++p)
            #pragma unroll
            for (int r = 0; r < 4; ++r) {
                int row = m0 + wr + i*16 + quad*4 + r;      // m89-verified C/D map
                int col = (vg0 + p)*16 + lr;
                float v  = acc[i][2*p][r];
                float gt = acc[i][2*p + 1][r];
                float y = v * (gt / (1.f + __expf(-gt)));
                yact[(size_t)row * NACT + col] = f2bf(y);
            }
}

// ---------------------------------------------------------------------------
// Scan pass 1 (partials only): one block per (b,k,chunk), 128 thr = 2 waves.
// Full conv+SiLU+RMS+phase compute but NO per-token stores -- r12 analysis:
// the 100 MB re/im round-trip costs >>10x the recompute (pass 2 re-derives
// values bitwise-identically). Output: chunk partial sums only (0.4 MB).
// ---------------------------------------------------------------------------
__global__ __launch_bounds__(128)
void scan_part(const float* __restrict__ zmem, const float* __restrict__ conv_w,
               const float* __restrict__ rms_scale, const float* __restrict__ theta_raw,
               const float* __restrict__ dslopes, const float* __restrict__ sscale,
               const float* __restrict__ tscale, float* __restrict__ part)
{
    int blk = blockIdx.x;            // = bk*16 + chunk
    int chunk = blk & (NCHUNK - 1);
    int bk = blk >> 4;
    int k = bk % K_;
    int b = bk / K_;
    int tid = threadIdx.x;
    int h = tid & 63;
    int tt = tid >> 6;               // wave -> token sub-range
    int l0 = chunk * CHLEN + tt * 64;

    int c  = k*H_ + h;
    int cs = DIM_MEM_ + k;

    float cw0 = conv_w[0*DMK + c], cw1 = conv_w[1*DMK + c];
    float cw2 = conv_w[2*DMK + c], cw3 = conv_w[3*DMK + c];
    float cs0 = conv_w[0*DMK + cs], cs1 = conv_w[1*DMK + cs];
    float cs2 = conv_w[2*DMK + cs], cs3 = conv_w[3*DMK + cs];
    float rs  = rms_scale[h];
    float th  = 0.001f + 2.999f * (1.f / (1.f + __expf(-theta_raw[c])));
    float ts  = tscale[k];
    float scl = sscale[k];
    float slope = log1pf(expf(dslopes[k]));

    const float* zb = zmem + (size_t)(b*L_) * DMK;

    float z3=0.f, z2=0.f, z1=0.f, s3=0.f, s2=0.f, s1=0.f;
    {
        int ll = l0 - 3;
        if (ll >= 0)     { z3 = zb[(size_t)ll*DMK + c];     s3 = zb[(size_t)ll*DMK + cs]; }
        if (ll + 1 >= 0) { z2 = zb[(size_t)(ll+1)*DMK + c]; s2 = zb[(size_t)(ll+1)*DMK + cs]; }
        if (ll + 2 >= 0) { z1 = zb[(size_t)(ll+2)*DMK + c]; s1 = zb[(size_t)(ll+2)*DMK + cs]; }
    }

    float sre = 0.f, sim = 0.f, spw = 0.f;

    for (int i0 = 0; i0 < 64; i0 += 8) {
        float zl[8], sl[8];
        #pragma unroll
        for (int j = 0; j < 8; ++j) {
            int l = l0 + i0 + j;
            zl[j] = zb[(size_t)l*DMK + c];
            sl[j] = zb[(size_t)l*DMK + cs];
        }
        #pragma unroll
        for (int j = 0; j < 8; ++j) {
            int l = l0 + i0 + j;
            float a3 = zl[j], b3 = sl[j];
            float acc  = cw0*z3 + cw1*z2 + cw2*z1 + cw3*a3;
            float acc2 = cs0*s3 + cs1*s2 + cs2*s1 + cs3*b3;
            z3 = z2; z2 = z1; z1 = a3;
            s3 = s2; s2 = s1; s1 = b3;

            float kv = acc / (1.f + __expf(-acc));          // silu (hw exp)
            float ss = kv * kv;
            #pragma unroll
            for (int off = 32; off > 0; off >>= 1)
                ss += __shfl_xor(ss, off, 64);
            float kn  = kv * rsqrtf(ss * (1.f/64.f) + 1e-6f) * rs;
            float phi = tanh_fast(kn * ts) * th;

            float s  = acc2 / (1.f + expf(-acc2));          // match original expf
            float lp = fminf(10.f, fmaxf(-10.f, scl * s));
            float pwv = expf(lp - slope * (float)(L_ - 1 - l));

            float kvw = kn * pwv;
            sre += kvw * __cosf(phi);
            sim += kvw * __sinf(phi);
            spw += pwv;
        }
    }

    // cross-wave combine -> chunk partials (layout: [0..63]=re, [64..127]=im)
    __shared__ float red[2][64], imd[2][64], pwd[2];
    red[tt][h] = sre; imd[tt][h] = sim;
    if (h == 0) pwd[tt] = spw;
    __syncthreads();
    size_t pb = (size_t)blk * PSTRIDE;
    if (tid < 64) part[pb + tid] = red[0][tid] + red[1][tid];
    else          part[pb + tid] = imd[0][tid - 64] + imd[1][tid - 64];
    if (tid == 0) part[pb + 128] = pwd[0] + pwd[1];
}

// ---------------------------------------------------------------------------
// Scan pass 2 (recompute + emit): prefix from partials, then walk the chunk's
// 128 tokens recomputing conv+SiLU+RMS+phase BITWISE-identically to pass 1
// (same expressions, same order), cumsum, emit bf16 summary directly.
// Wave 0 (pi=0) carries re, wave 1 im; pi branch is wave-uniform; each wave's
// 64 lanes = the 64 h's of one token -> per-wave shfl RMS reduce.
// ---------------------------------------------------------------------------
__global__ __launch_bounds__(128)
void scan_emit(const float* __restrict__ zmem, const float* __restrict__ conv_w,
               const float* __restrict__ rms_scale, const float* __restrict__ theta_raw,
               const float* __restrict__ dslopes, const float* __restrict__ sscale,
               const float* __restrict__ tscale, const float* __restrict__ part,
               ushort* __restrict__ summary)
{
    int blk = blockIdx.x;
    int chunk = blk & (NCHUNK - 1);
    int bk = blk >> 4;
    int k = bk % K_;
    int b = bk / K_;
    int tid = threadIdx.x;
    int h = tid & 63;
    int pi = tid >> 6;               // 0: re-channel, 1: im-channel
    int l0 = chunk * CHLEN;

    // prefix from preceding chunks (same layout/order as before)
    float acc = 0.f, dacc = 0.f;
    size_t pb0 = (size_t)(bk * NCHUNK) * PSTRIDE;
    for (int cn = 0; cn < chunk; ++cn) {
        acc  += part[pb0 + (size_t)cn*PSTRIDE + tid];
        dacc += part[pb0 + (size_t)cn*PSTRIDE + 128];
    }

    int c  = k*H_ + h;
    int cs = DIM_MEM_ + k;

    float cw0 = conv_w[0*DMK + c], cw1 = conv_w[1*DMK + c];
    float cw2 = conv_w[2*DMK + c], cw3 = conv_w[3*DMK + c];
    float cs0 = conv_w[0*DMK + cs], cs1 = conv_w[1*DMK + cs];
    float cs2 = conv_w[2*DMK + cs], cs3 = conv_w[3*DMK + cs];
    float rs  = rms_scale[h];
    float th  = 0.001f + 2.999f * (1.f / (1.f + __expf(-theta_raw[c])));
    float ts  = tscale[k];
    float scl = sscale[k];
    float slope = log1pf(expf(dslopes[k]));

    const float* zb = zmem + (size_t)(b*L_) * DMK;

    float z3=0.f, z2=0.f, z1=0.f, s3=0.f, s2=0.f, s1=0.f;
    {
        int ll = l0 - 3;
        if (ll >= 0)     { z3 = zb[(size_t)ll*DMK + c];     s3 = zb[(size_t)ll*DMK + cs]; }
        if (ll + 1 >= 0) { z2 = zb[(size_t)(ll+1)*DMK + c]; s2 = zb[(size_t)(ll+1)*DMK + cs]; }
        if (ll + 2 >= 0) { z1 = zb[(size_t)(ll+2)*DMK + c]; s1 = zb[(size_t)(ll+2)*DMK + cs]; }
    }

    int outch = 2*(k*H_ + h) + pi;

    for (int i0 = 0; i0 < CHLEN; i0 += 8) {
        float zl[8], sl[8];
        #pragma unroll
        for (int j = 0; j < 8; ++j) {
            int l = l0 + i0 + j;
            zl[j] = zb[(size_t)l*DMK + c];
            sl[j] = zb[(size_t)l*DMK + cs];
        }
        #pragma unroll
        for (int j = 0; j < 8; ++j) {
            int l = l0 + i0 + j;
            float a3 = zl[j], b3 = sl[j];
            float cacc = cw0*z3 + cw1*z2 + cw2*z1 + cw3*a3;
            float acc2 = cs0*s3 + cs1*s2 + cs2*s1 + cs3*b3;
            z3 = z2; z2 = z1; z1 = a3;
            s3 = s2; s2 = s1; s1 = b3;

            float kv = cacc / (1.f + __expf(-cacc));        // silu (hw exp)
            float ss = kv * kv;
            #pragma unroll
            for (int off = 32; off > 0; off >>= 1)
                ss += __shfl_xor(ss, off, 64);
            float kn  = kv * rsqrtf(ss * (1.f/64.f) + 1e-6f) * rs;
            float phi = tanh_fast(kn * ts) * th;

            float s  = acc2 / (1.f + expf(-acc2));          // match original expf
            float lp = fminf(10.f, fmaxf(-10.f, scl * s));
            float pwv = expf(lp - slope * (float)(L_ - 1 - l));

            float kvw = kn * pwv;
            float val = pi ? (kvw * __sinf(phi)) : (kvw * __cosf(phi));
            acc += val; dacc += pwv;
            float inv = 1.f / fmaxf(dacc, 1e-4f);
            summary[((size_t)(b*L_ + l))*NSUM + outch] = f2bf(acc * inv);
        }
    }
}

// ---------------------------------------------------------------------------
extern "C" void kernel_launch(void* const* d_in, const int* in_sizes, int n_in,
                              void* d_out, int out_size, void* d_ws, size_t ws_size,
                              hipStream_t stream)
{
    const float* x         = (const float*)d_in[0];
    const float* W_in      = (const float*)d_in[1];
    const float* conv_w    = (const float*)d_in[2];
    const float* rms_scale = (const float*)d_in[3];
    const float* theta_raw = (const float*)d_in[4];
    const float* dslopes   = (const float*)d_in[5];
    const float* sscale    = (const float*)d_in[6];
    const float* tscale    = (const float*)d_in[7];
    const float* W_sw      = (const float*)d_in[8];
    const float* W_out     = (const float*)d_in[9];
    float* out = (float*)d_out;
    char* ws   = (char*)d_ws;

    // Workspace (byte offsets, 256-aligned). Total 102.1 MB. re/im/pw buffers
    // ELIMINATED (recompute); summary moved off the zmem alias (scan_emit now
    // reads zmem while writing summary). yact overlays zmem (dead by gemm2).
    ushort* yact    = (ushort*)(ws + 0);           // 37,748,736 B [8192][2304]
    float*  zmem    = (float*) (ws + 0);           // 25,559,040 B (dead before yact written)
    ushort* summary = (ushort*)(ws + 37748736);    // 25,165,824 B -> ends 62,914,560
    float*  part    = (float*) (ws + 62914560);    //    405,504 B -> ends 63,320,064
    ushort* xb      = (ushort*)(ws + 63320064);    // 12,582,912 B -> ends 75,902,976
    ushort* WiCat   = (ushort*)(ws + 75902976);    //  7,077,888 B -> ends 82,980,864
    ushort* WsCat   = (ushort*)(ws + 82980864);    // 14,155,776 B -> ends 97,136,640
    ushort* WoT     = (ushort*)(ws + 97136640);    //  3,538,944 B -> ends 100,675,584
    ushort* WimT    = (ushort*)(ws + 100675584);   //  1,376,256 B -> ends 102,051,840

    // ---- merged prep job table (64-wide k-tiles) ----
    PrepJobs J{};
    J.W[0]=W_in;  J.out[0]=WiCat; J.ldw[0]=5388; J.Kd[0]=768;  J.colbase[0]=780; J.remap[0]=1; J.ntx[0]=144;
    J.W[1]=W_sw;  J.out[1]=WsCat; J.ldw[1]=4608; J.Kd[1]=1536; J.colbase[1]=0;   J.remap[1]=1; J.ntx[1]=144;
    J.W[2]=W_out; J.out[2]=WoT;   J.ldw[2]=768;  J.Kd[2]=2304; J.colbase[2]=0;   J.remap[2]=0; J.ntx[2]=24;
    J.W[3]=W_in;  J.out[3]=WimT;  J.ldw[3]=5388; J.Kd[3]=768;  J.colbase[3]=0;   J.remap[3]=0; J.ntx[3]=28;
    int tiles[4] = {144*12, 144*24, 24*36, 28*12};   // k-tiles = Kd/64
    J.start[0] = 0;
    for (int j = 0; j < 4; ++j) J.start[j+1] = J.start[j] + tiles[j];
    J.start[5] = J.start[4];
    J.start[6] = J.start[4];
    J.cast_in = x; J.cast_out = xb; J.n8 = NT*D_/8;
    int nblk = J.start[6] + (J.n8 + 255)/256;

    dim3 blk(256);
    // 0) all preps in one launch
    prep_all<<<dim3(nblk), blk, 0, stream>>>(J);
    // 1) z_mem = x @ W_in[:, :780]  (1-phase pipelined MFMA + XCD swizzle)
    gemm13_1ph<<<dim3(7, 64), blk, 0, stream>>>(xb, WimT, zmem, 768, 780, 780);
    // 2) chunk partial sums (full compute, no per-token stores)
    scan_part<<<dim3(B_*K_*NCHUNK), dim3(128), 0, stream>>>(
        zmem, conv_w, rms_scale, theta_raw, dslopes, sscale, tscale, part);
    // 3) prefix + recompute + emit bf16 summary
    scan_emit<<<dim3(B_*K_*NCHUNK), dim3(128), 0, stream>>>(
        zmem, conv_w, rms_scale, theta_raw, dslopes, sscale, tscale, part, summary);
    // 4) fused spectral+skip single-phase pipelined GEMM (no swizzle) -> yact
    gemm2_1ph<<<dim3(24, 64), dim3(256), 0, stream>>>(summary, xb, WsCat, WiCat, yact);
    // 5) out = yact @ W_out  (1-phase pipelined MFMA + XCD swizzle)
    gemm13_1ph<<<dim3(6, 64), blk, 0, stream>>>(yact, WoT, out, 2304, 768, 768);
}

// Round 14
// 373.540 us; speedup vs baseline: 1.1676x; 1.1676x over previous
//
#include <hip/hip_runtime.h>
#include <hip/hip_bf16.h>

// Problem constants (B,L,D)=(4,2048,768), K=12, M=1, CK=4, H=64
#define B_       4
#define L_       2048
#define D_       768
#define K_       12
#define H_       64
#define CK_      4
#define DIM_MEM_ 768
#define DMK      780        // DIM_MEM + K
#define NT       (B_*L_)    // 8192 tokens
#define NSUM     1536       // 2*K*H  (summary width)
#define NACT     2304       // K*192  (y_act width)
#define NCHUNK   32         // r14: 16->32, doubles scan-chain TLP (r13 showed latency-bound)
#define CHLEN    (L_/NCHUNK)  // 64
#define PSTRIDE  132

typedef __attribute__((ext_vector_type(8))) short          bf16x8;
typedef __attribute__((ext_vector_type(8))) unsigned short u16x8;
typedef __attribute__((ext_vector_type(4))) float          f32x4;

__device__ __forceinline__ ushort f2bf(float v) {
    __hip_bfloat16 h = __float2bfloat16(v);
    return *reinterpret_cast<ushort*>(&h);
}
// fast tanh via hw exp; safe for any x
__device__ __forceinline__ float tanh_fast(float x) {
    float t = __expf(-2.f * fabsf(x));
    float r = (1.f - t) / (1.f + t);
    return copysignf(r, x);
}

// ---------------------------------------------------------------------------
// Merged prep: transpose-cast jobs (32n x 64k LDS tiles, ushort8 stores) +
// x->bf16 cast (2xfloat4 -> ushort8). r12-measured neutral; kept.
// remap==1: interleaved val/gate layout for the fused spectral GEMM.
// ---------------------------------------------------------------------------
struct PrepJobs {
    const float* W[6];
    ushort*      out[6];
    int ldw[6], Kd[6], colbase[6], remap[6], ntx[6];
    int start[7];
    const float* cast_in;
    ushort*      cast_out;
    int n8;                         // number of ushort8 groups in cast job
};

__global__ __launch_bounds__(256)
void prep_all(PrepJobs J)
{
    int blk = blockIdx.x;
    if (blk >= J.start[6]) {                       // cast job: 2 float4 -> ushort8
        int i = (blk - J.start[6]) * 256 + threadIdx.x;
        if (i < J.n8) {
            float4 v0 = reinterpret_cast<const float4*>(J.cast_in)[2*i];
            float4 v1 = reinterpret_cast<const float4*>(J.cast_in)[2*i + 1];
            u16x8 o;
            o[0] = f2bf(v0.x); o[1] = f2bf(v0.y); o[2] = f2bf(v0.z); o[3] = f2bf(v0.w);
            o[4] = f2bf(v1.x); o[5] = f2bf(v1.y); o[6] = f2bf(v1.z); o[7] = f2bf(v1.w);
            reinterpret_cast<u16x8*>(J.cast_out)[i] = o;
        }
        return;
    }
    int j = 0;
    while (blk >= J.start[j + 1]) ++j;
    int rel = blk - J.start[j];
    int ntx = J.ntx[j];
    int n0 = (rel % ntx) * 32, k0 = (rel / ntx) * 64;
    const float* W = J.W[j];
    int ldw = J.ldw[j], Kd = J.Kd[j], colbase = J.colbase[j], remap = J.remap[j];
    ushort* out = J.out[j];

    __shared__ float tile[64][33];                 // [k_local][n_local], +1 pad
    int tx = threadIdx.x & 31, ty = threadIdx.x >> 5;   // read: 32n x 8k, 8 iters
    int n = n0 + tx;
    int c;
    if (remap) {
        int grp = n >> 5, which = (n >> 4) & 1, nn = (grp << 4) + (n & 15);
        c = colbase + (nn / 192) * 384 + which * 192 + (nn % 192);
    } else {
        c = colbase + n;
    }
    #pragma unroll
    for (int r = 0; r < 8; ++r)
        tile[ty + r*8][tx] = W[(size_t)(k0 + ty + r*8) * ldw + c];
    __syncthreads();
    // write: thread (nl = tid>>3, kg = tid&7) emits out[n0+nl][k0+kg*8 .. +7]
    int nl = threadIdx.x >> 3, kg = threadIdx.x & 7;
    u16x8 o;
    #pragma unroll
    for (int t = 0; t < 8; ++t)
        o[t] = f2bf(tile[kg*8 + t][nl]);
    *reinterpret_cast<u16x8*>(&out[(size_t)(n0 + nl) * Kd + k0 + kg*8]) = o;
}

// ---------------------------------------------------------------------------
// global_load_lds staging macro (width 16)
// ---------------------------------------------------------------------------
#define GLOAD16(gp, dp) __builtin_amdgcn_global_load_lds( \
    (__attribute__((address_space(1))) const void*)(gp),  \
    (__attribute__((address_space(3))) void*)(dp), 16, 0, 0)

// ---------------------------------------------------------------------------
// bf16 MFMA GEMM, 1-phase pipelined + 2 blocks/CU + bijective XCD swizzle.
// Swizzle KEPT here (r10/r11 A/B: helps when streamed operand is L2-resident).
// ---------------------------------------------------------------------------
__device__ __forceinline__ void g13_stage(ushort* dst, const ushort* src, int kd)
{
    #pragma unroll
    for (int s = 0; s < 4; ++s)
        GLOAD16(src + (size_t)(32*s)*kd, dst + 2048*s);
}

__global__ __launch_bounds__(256, 2)
void gemm13_1ph(const ushort* __restrict__ A, const ushort* __restrict__ BT,
                float* __restrict__ C, int Kd, int N, int ldc)
{
    __shared__ ushort lds[32768];
    const int tid  = threadIdx.x;
    const int lane = tid & 63, wave = tid >> 6;
    const int lr = lane & 15, quad = lane >> 4, rx = lr & 7;
    const int wr = (wave >> 1) * 64, wc = (wave & 1) * 64;

    // bijective chunked XCD swizzle (nwg % 8 == 0 at all call sites)
    const int nwgx = gridDim.x;
    const int orig = blockIdx.x + blockIdx.y * nwgx;
    const int cpx  = (nwgx * gridDim.y) >> 3;
    const int swz  = (orig & 7) * cpx + (orig >> 3);
    const int m0 = (swz / nwgx) * 128, n0 = (swz % nwgx) * 128;
    const int NKT = Kd >> 6;

    const int sr = tid >> 3;             // 0..31
    const int sc = (tid & 7) ^ (sr & 7);
    const ushort* pA = A  + (size_t)(m0 + sr) * Kd + sc * 8;
    const ushort* pB = BT + (size_t)(n0 + sr) * Kd + sc * 8;

    f32x4 acc[4][4] = {};
    const int ca0 = (quad ^ rx) * 8;
    const int ca1 = ((4 + quad) ^ rx) * 8;

    g13_stage(lds + wave*512,         pA, Kd);
    g13_stage(lds + 16384 + wave*512, pB, Kd);
    asm volatile("s_waitcnt vmcnt(0)" ::: "memory");
    __builtin_amdgcn_s_barrier();

    #pragma unroll 1
    for (int g = 0; g < NKT; ++g) {
        const ushort* Ab = lds + (g & 1) * 8192;
        const ushort* Bb = lds + 16384 + (g & 1) * 8192;

        int nk = (g + 1 < NKT) ? g + 1 : NKT - 1;
        g13_stage(lds + ((g + 1) & 1) * 8192 + wave*512,         pA + nk*64, Kd);
        g13_stage(lds + 16384 + ((g + 1) & 1) * 8192 + wave*512, pB + nk*64, Kd);

        bf16x8 af[4][2], bf[4][2];
        #pragma unroll
        for (int i = 0; i < 4; ++i) {
            const ushort* p = Ab + (wr + i*16 + lr) * 64;
            af[i][0] = *reinterpret_cast<const bf16x8*>(p + ca0);
            af[i][1] = *reinterpret_cast<const bf16x8*>(p + ca1);
        }
        #pragma unroll
        for (int j = 0; j < 4; ++j) {
            const ushort* p = Bb + (wc + j*16 + lr) * 64;
            bf[j][0] = *reinterpret_cast<const bf16x8*>(p + ca0);
            bf[j][1] = *reinterpret_cast<const bf16x8*>(p + ca1);
        }
        __builtin_amdgcn_s_setprio(1);
        #pragma unroll
        for (int ks = 0; ks < 2; ++ks)
            #pragma unroll
            for (int i = 0; i < 4; ++i)
                #pragma unroll
                for (int j = 0; j < 4; ++j)
                    acc[i][j] = __builtin_amdgcn_mfma_f32_16x16x32_bf16(
                                    af[i][ks], bf[j][ks], acc[i][j], 0, 0, 0);
        __builtin_amdgcn_s_setprio(0);

        asm volatile("s_waitcnt vmcnt(0)" ::: "memory");
        __builtin_amdgcn_s_barrier();
    }

    #pragma unroll
    for (int i = 0; i < 4; ++i)
        #pragma unroll
        for (int j = 0; j < 4; ++j)
            #pragma unroll
            for (int r = 0; r < 4; ++r) {
                int row = m0 + wr + i*16 + quad*4 + r;      // m89-verified C/D map
                int col = n0 + wc + j*16 + lr;
                if (col < N)
                    C[(size_t)row * ldc + col] = acc[i][j][r];
            }
}

// ---------------------------------------------------------------------------
// Fused spectral+skip GEMM, single-phase pipelined + 2 blocks/CU (proven
// ~145us, MfmaUtil 56%, VGPR 100). No XCD swizzle (r10: hurts, 21MB B >> L2).
// ---------------------------------------------------------------------------
#define G2NKT 36   // 24 k-tiles of summary (K=1536) + 12 of x (K=768)

__device__ __forceinline__ void g2_stageA(ushort* lds_, int kt,
                                          const ushort* pAs, const ushort* pAx,
                                          int wave, int part)
{
    int ktc = kt > (G2NKT-1) ? (G2NKT-1) : kt;   // clamp src; dest parity uses kt
    const ushort* g; size_t kd;
    if (ktc < 24) { g = pAs + ktc*64;      kd = 1536; }
    else          { g = pAx + (ktc-24)*64; kd = 768;  }
    g += (size_t)(part * 64) * kd;               // rows part*64 .. part*64+63
    ushort* d = lds_ + (kt & 1) * 8192 + part * 4096 + wave * 512;
    GLOAD16(g,           d);
    GLOAD16(g + 32*kd,   d + 2048);
}

__device__ __forceinline__ void g2_stageB(ushort* lds_, int kt,
                                          const ushort* pBs, const ushort* pBx,
                                          int wave)
{
    int ktc = kt > (G2NKT-1) ? (G2NKT-1) : kt;
    const ushort* g; size_t kd;
    if (ktc < 24) { g = pBs + ktc*64;      kd = 1536; }
    else          { g = pBx + (ktc-24)*64; kd = 768;  }
    ushort* d = lds_ + 16384 + (kt & 1) * 12288 + wave * 512;
    #pragma unroll
    for (int s = 0; s < 6; ++s)
        GLOAD16(g + (size_t)(32*s)*kd, d + 2048*s);
}

__global__ __launch_bounds__(256, 2)
void gemm2_1ph(const ushort* __restrict__ Sm, const ushort* __restrict__ Xb,
               const ushort* __restrict__ WsC, const ushort* __restrict__ WiC,
               ushort* __restrict__ yact)
{
    __shared__ ushort lds[40960];
    const int tid  = threadIdx.x;
    const int lane = tid & 63, wave = tid >> 6;      // wave 0..3
    const int lr = lane & 15, quad = lane >> 4, rx = lr & 7;
    const int wr = (wave >> 1) * 64;     // 0,64
    const int wc = (wave & 1) * 96;      // 0,96
    const int m0 = blockIdx.y * 128, n0 = blockIdx.x * 192;

    const int sr = tid >> 3;             // 0..31
    const int sc = (tid & 7) ^ (sr & 7);
    const ushort* pAs = Sm  + (size_t)(m0 + sr) * 1536 + sc * 8;
    const ushort* pAx = Xb  + (size_t)(m0 + sr) * 768  + sc * 8;
    const ushort* pBs = WsC + (size_t)(n0 + sr) * 1536 + sc * 8;
    const ushort* pBx = WiC + (size_t)(n0 + sr) * 768  + sc * 8;

    f32x4 acc[4][6] = {};
    const int ca0 = (quad ^ rx) * 8;
    const int ca1 = ((4 + quad) ^ rx) * 8;

    g2_stageA(lds, 0, pAs, pAx, wave, 0);
    g2_stageA(lds, 0, pAs, pAx, wave, 1);
    g2_stageB(lds, 0, pBs, pBx, wave);
    asm volatile("s_waitcnt vmcnt(0)" ::: "memory");
    __builtin_amdgcn_s_barrier();

    #pragma unroll 1
    for (int g = 0; g < G2NKT; ++g) {
        const ushort* Ab = lds + (g & 1) * 8192;
        const ushort* Bb = lds + 16384 + (g & 1) * 12288;

        g2_stageA(lds, g + 1, pAs, pAx, wave, 0);
        g2_stageA(lds, g + 1, pAs, pAx, wave, 1);
        g2_stageB(lds, g + 1, pBs, pBx, wave);

        bf16x8 af[4][2], bfr[6][2];
        #pragma unroll
        for (int i = 0; i < 4; ++i) {
            const ushort* p = Ab + (wr + i*16 + lr) * 64;
            af[i][0] = *reinterpret_cast<const bf16x8*>(p + ca0);
            af[i][1] = *reinterpret_cast<const bf16x8*>(p + ca1);
        }
        #pragma unroll
        for (int j = 0; j < 6; ++j) {
            const ushort* p = Bb + (wc + j*16 + lr) * 64;
            bfr[j][0] = *reinterpret_cast<const bf16x8*>(p + ca0);
            bfr[j][1] = *reinterpret_cast<const bf16x8*>(p + ca1);
        }
        __builtin_amdgcn_s_setprio(1);
        #pragma unroll
        for (int ks = 0; ks < 2; ++ks)
            #pragma unroll
            for (int i = 0; i < 4; ++i)
                #pragma unroll
                for (int j = 0; j < 6; ++j)
                    acc[i][j] = __builtin_amdgcn_mfma_f32_16x16x32_bf16(
                                    af[i][ks], bfr[j][ks], acc[i][j], 0, 0, 0);
        __builtin_amdgcn_s_setprio(0);

        asm volatile("s_waitcnt vmcnt(0)" ::: "memory");
        __builtin_amdgcn_s_barrier();
    }

    // epilogue: lane-local (val,gate) pairs -> gated SiLU -> bf16
    const int vg0 = (n0 + wc) >> 5;
    #pragma unroll
    for (int i = 0; i < 4; ++i)
        #pragma unroll
        for (int p = 0; p < 3; ++p)
            #pragma unroll
            for (int r = 0; r < 4; ++r) {
                int row = m0 + wr + i*16 + quad*4 + r;      // m89-verified C/D map
                int col = (vg0 + p)*16 + lr;
                float v  = acc[i][2*p][r];
                float gt = acc[i][2*p + 1][r];
                float y = v * (gt / (1.f + __expf(-gt)));
                yact[(size_t)row * NACT + col] = f2bf(y);
            }
}

// ---------------------------------------------------------------------------
// Fused token+scan pass 1 (r11-proven structure, NCHUNK=32): one block per
// (b,k,chunk), 128 thr = 2 waves; wave tt owns tokens [chunk*64 + tt*32, +32).
// conv+SiLU+RMSNorm+phase, stores re/im chunk-local + chunk partial sums.
// r13 lesson: recompute instead of store REGRESSED 60us (latency-bound chain)
// -> keep stores; double TLP instead (768->1536 blocks).
// ---------------------------------------------------------------------------
__global__ __launch_bounds__(128)
void token_scan1(const float* __restrict__ zmem, const float* __restrict__ conv_w,
                 const float* __restrict__ rms_scale, const float* __restrict__ theta_raw,
                 const float* __restrict__ dslopes, const float* __restrict__ sscale,
                 const float* __restrict__ tscale,
                 float* __restrict__ reN, float* __restrict__ imN,
                 float* __restrict__ pwN, float* __restrict__ part)
{
    int blk = blockIdx.x;            // = bk*NCHUNK + chunk
    int chunk = blk & (NCHUNK - 1);
    int bk = blk >> 5;
    int k = bk % K_;
    int b = bk / K_;
    int tid = threadIdx.x;
    int h = tid & 63;
    int tt = tid >> 6;               // wave -> token sub-range (32 tokens)
    int l0 = chunk * CHLEN + tt * 32;

    int c  = k*H_ + h;
    int cs = DIM_MEM_ + k;

    float cw0 = conv_w[0*DMK + c], cw1 = conv_w[1*DMK + c];
    float cw2 = conv_w[2*DMK + c], cw3 = conv_w[3*DMK + c];
    float cs0 = conv_w[0*DMK + cs], cs1 = conv_w[1*DMK + cs];
    float cs2 = conv_w[2*DMK + cs], cs3 = conv_w[3*DMK + cs];
    float rs  = rms_scale[h];
    float th  = 0.001f + 2.999f * (1.f / (1.f + __expf(-theta_raw[c])));
    float ts  = tscale[k];
    float scl = sscale[k];
    float slope = log1pf(expf(dslopes[k]));

    const float* zb = zmem + (size_t)(b*L_) * DMK;

    // rolling window carry: z3=row(l-3), z2=row(l-2), z1=row(l-1)
    float z3=0.f, z2=0.f, z1=0.f, s3=0.f, s2=0.f, s1=0.f;
    {
        int ll = l0 - 3;
        if (ll >= 0)     { z3 = zb[(size_t)ll*DMK + c];     s3 = zb[(size_t)ll*DMK + cs]; }
        if (ll + 1 >= 0) { z2 = zb[(size_t)(ll+1)*DMK + c]; s2 = zb[(size_t)(ll+1)*DMK + cs]; }
        if (ll + 2 >= 0) { z1 = zb[(size_t)(ll+2)*DMK + c]; s1 = zb[(size_t)(ll+2)*DMK + cs]; }
    }

    float sre = 0.f, sim = 0.f, spw = 0.f;
    size_t obase = (size_t)blk * (CHLEN*H_) + (size_t)(tt*32)*H_ + h;

    for (int i0 = 0; i0 < 32; i0 += 8) {
        float zl[8], sl[8];
        #pragma unroll
        for (int j = 0; j < 8; ++j) {
            int l = l0 + i0 + j;
            zl[j] = zb[(size_t)l*DMK + c];
            sl[j] = zb[(size_t)l*DMK + cs];
        }
        #pragma unroll
        for (int j = 0; j < 8; ++j) {
            int l = l0 + i0 + j;
            float a3 = zl[j], b3 = sl[j];
            float acc  = cw0*z3 + cw1*z2 + cw2*z1 + cw3*a3;
            float acc2 = cs0*s3 + cs1*s2 + cs2*s1 + cs3*b3;
            z3 = z2; z2 = z1; z1 = a3;       // roll the windows (pure scalars)
            s3 = s2; s2 = s1; s1 = b3;

            float kv = acc / (1.f + __expf(-acc));          // silu (hw exp)
            float ss = kv * kv;
            #pragma unroll
            for (int off = 32; off > 0; off >>= 1)
                ss += __shfl_xor(ss, off, 64);
            float kn  = kv * rsqrtf(ss * (1.f/64.f) + 1e-6f) * rs;
            float phi = tanh_fast(kn * ts) * th;

            float s  = acc2 / (1.f + expf(-acc2));          // match original expf
            float lp = fminf(10.f, fmaxf(-10.f, scl * s));
            float pwv = expf(lp - slope * (float)(L_ - 1 - l));

            float kvw = kn * pwv;
            float rev = kvw * __cosf(phi);
            float imv = kvw * __sinf(phi);
            reN[obase + (size_t)(i0 + j)*H_] = rev;
            imN[obase + (size_t)(i0 + j)*H_] = imv;
            sre += rev; sim += imv; spw += pwv;
            if (h == 0) pwN[(size_t)bk * L_ + l] = pwv;
        }
    }

    // cross-wave combine -> chunk partials ([0..63]=re, [64..127]=im)
    __shared__ float red[2][64], imd[2][64], pwd[2];
    red[tt][h] = sre; imd[tt][h] = sim;
    if (h == 0) pwd[tt] = spw;
    __syncthreads();
    size_t pb = (size_t)blk * PSTRIDE;
    if (tid < 64) part[pb + tid] = red[0][tid] + red[1][tid];
    else          part[pb + tid] = imd[0][tid - 64] + imd[1][tid - 64];
    if (tid == 0) part[pb + 128] = pwd[0] + pwd[1];
}

// ---------------------------------------------------------------------------
// Scan pass 2 on the chunk-local layout: prefix from partials, emit bf16
// summary. Serial cumsum now 64 tokens/thread (was 128).
// ---------------------------------------------------------------------------
__global__ __launch_bounds__(128)
void scan_final2(const float* __restrict__ pwN, const float* __restrict__ reN,
                 const float* __restrict__ imN, const float* __restrict__ part,
                 ushort* __restrict__ summary)
{
    int blk = blockIdx.x;
    int chunk = blk & (NCHUNK - 1);
    int bk = blk >> 5;
    int k = bk % K_;
    int b = bk / K_;
    int tid = threadIdx.x;
    int h = tid & 63;
    int pi = tid >> 6;
    const float* __restrict__ src = pi ? imN : reN;
    int l0 = chunk * CHLEN;

    float acc = 0.f, dacc = 0.f;
    size_t pb0 = (size_t)(bk * NCHUNK) * PSTRIDE;
    for (int cn = 0; cn < chunk; ++cn) {
        acc  += part[pb0 + (size_t)cn*PSTRIDE + tid];
        dacc += part[pb0 + (size_t)cn*PSTRIDE + 128];
    }

    size_t base  = (size_t)blk * (CHLEN*H_) + h;
    size_t dbase = (size_t)bk * L_ + l0;
    int outch = 2*(k*H_ + h) + pi;
    for (int i0 = 0; i0 < CHLEN; i0 += 8) {
        float v[8], d[8];
        #pragma unroll
        for (int j = 0; j < 8; ++j) {
            v[j] = src[base + (size_t)(i0 + j)*H_];
            d[j] = pwN[dbase + i0 + j];
        }
        #pragma unroll
        for (int j = 0; j < 8; ++j) {
            acc += v[j]; dacc += d[j];
            float inv = 1.f / fmaxf(dacc, 1e-4f);
            summary[((size_t)(b*L_ + l0 + i0 + j))*NSUM + outch] = f2bf(acc * inv);
        }
    }
}

// ---------------------------------------------------------------------------
extern "C" void kernel_launch(void* const* d_in, const int* in_sizes, int n_in,
                              void* d_out, int out_size, void* d_ws, size_t ws_size,
                              hipStream_t stream)
{
    const float* x         = (const float*)d_in[0];
    const float* W_in      = (const float*)d_in[1];
    const float* conv_w    = (const float*)d_in[2];
    const float* rms_scale = (const float*)d_in[3];
    const float* theta_raw = (const float*)d_in[4];
    const float* dslopes   = (const float*)d_in[5];
    const float* sscale    = (const float*)d_in[6];
    const float* tscale    = (const float*)d_in[7];
    const float* W_sw      = (const float*)d_in[8];
    const float* W_out     = (const float*)d_in[9];
    float* out = (float*)d_out;
    char* ws   = (char*)d_ws;

    // Workspace (byte offsets, 256-aligned). Peak 115.8 MB (< proven 127).
    float*  zmem    = (float*) (ws + 0);           // NT*780 f32   = 25,559,040 B
    ushort* summary = (ushort*)(ws + 0);           // alias (zmem dead): 25,165,824 B
    float*  pw      = (float*) (ws + 25559040);    //   393,216 B  [bk][l]
    float*  re      = (float*) (ws + 25952256);    // 25,165,824 B [blk][tok][h]
    float*  im      = (float*) (ws + 51118080);    // 25,165,824 B
    ushort* yact    = (ushort*)(ws + 25952256);    // alias re+im (dead): 37,748,736 B
    float*  part    = (float*) (ws + 76283904);    //   811,008 B (1536 * 132 * 4)
    ushort* xb      = (ushort*)(ws + 77094912);    // 12,582,912 B
    ushort* WiCat   = (ushort*)(ws + 89677824);    //  7,077,888 B  [4608][768]  val/gate interleaved
    ushort* WsCat   = (ushort*)(ws + 96755712);    // 14,155,776 B  [4608][1536] val/gate interleaved
    ushort* WoT     = (ushort*)(ws + 110911488);   //  3,538,944 B  [768][2304]
    ushort* WimT    = (ushort*)(ws + 114450432);   //  1,376,256 B  [896][768] (pad)

    // ---- merged prep job table (64-wide k-tiles) ----
    PrepJobs J{};
    J.W[0]=W_in;  J.out[0]=WiCat; J.ldw[0]=5388; J.Kd[0]=768;  J.colbase[0]=780; J.remap[0]=1; J.ntx[0]=144;
    J.W[1]=W_sw;  J.out[1]=WsCat; J.ldw[1]=4608; J.Kd[1]=1536; J.colbase[1]=0;   J.remap[1]=1; J.ntx[1]=144;
    J.W[2]=W_out; J.out[2]=WoT;   J.ldw[2]=768;  J.Kd[2]=2304; J.colbase[2]=0;   J.remap[2]=0; J.ntx[2]=24;
    J.W[3]=W_in;  J.out[3]=WimT;  J.ldw[3]=5388; J.Kd[3]=768;  J.colbase[3]=0;   J.remap[3]=0; J.ntx[3]=28;
    int tiles[4] = {144*12, 144*24, 24*36, 28*12};   // k-tiles = Kd/64
    J.start[0] = 0;
    for (int j = 0; j < 4; ++j) J.start[j+1] = J.start[j] + tiles[j];
    J.start[5] = J.start[4];
    J.start[6] = J.start[4];
    J.cast_in = x; J.cast_out = xb; J.n8 = NT*D_/8;
    int nblk = J.start[6] + (J.n8 + 255)/256;

    dim3 blk(256);
    // 0) all preps in one launch
    prep_all<<<dim3(nblk), blk, 0, stream>>>(J);
    // 1) z_mem = x @ W_in[:, :780]  (1-phase pipelined MFMA + XCD swizzle)
    gemm13_1ph<<<dim3(7, 64), blk, 0, stream>>>(xb, WimT, zmem, 768, 780, 780);
    // 2) fused conv+silu+rmsnorm+phase + chunk partial sums (1x zmem read)
    token_scan1<<<dim3(B_*K_*NCHUNK), dim3(128), 0, stream>>>(
        zmem, conv_w, rms_scale, theta_raw, dslopes, sscale, tscale,
        re, im, pw, part);
    // 3) prefix + emit summary (bf16)
    scan_final2<<<dim3(B_*K_*NCHUNK), dim3(128), 0, stream>>>(pw, re, im, part, summary);
    // 4) fused spectral+skip single-phase pipelined GEMM (no swizzle) -> yact
    gemm2_1ph<<<dim3(24, 64), dim3(256), 0, stream>>>(summary, xb, WsCat, WiCat, yact);
    // 5) out = yact @ W_out  (1-phase pipelined MFMA + XCD swizzle)
    gemm13_1ph<<<dim3(6, 64), blk, 0, stream>>>(yact, WoT, out, 2304, 768, 768);
}